// Round 11
// baseline (61.423 us; speedup 1.0000x reference)
//
#include <hip/hip_runtime.h>
#include <math.h>

typedef float v2f __attribute__((ext_vector_type(2)));

#define N_POINTS 32768
#define NUM_EMBED 8192
#define NPAIRS 4096
#define CH 64                                // chunks (fits 64-bit survivor mask)
#define CPC (NUM_EMBED / CH)                 // 128 candidates per chunk
#define PAIRS (NPAIRS / CH)                  // 64 pairs per chunk
#define CPB 8                                // chunks per filter block
#define FPPT 2                               // filter points per thread
#define RB 512                               // resolve block threads (8 waves)
#define CSTRIDE 4096                         // 64*64, channel stride in z [B,C,H,W]

// ---------------- kernel A: build pair-interleaved codebook (bits preserved)
__global__ void vq_prep_kernel(const float4* __restrict__ E, v2f* __restrict__ Epk) {
    int p = blockIdx.x * 256 + threadIdx.x;
    if (p < NPAIRS) {
        float4 a = E[2 * p];
        float4 b = E[2 * p + 1];
        Epk[4 * p + 0] = (v2f){a.x, b.x};
        Epk[4 * p + 1] = (v2f){a.y, b.y};
        Epk[4 * p + 2] = (v2f){a.z, b.z};
        Epk[4 * p + 3] = (v2f){a.w, b.w};
    }
}

// packed f32 ops forced via inline asm (per-half IEEE rn, bit-identical to scalar chain)
__device__ __forceinline__ v2f pk_mul(v2f a, v2f b) {
    v2f d; asm("v_pk_mul_f32 %0, %1, %2" : "=v"(d) : "v"(a), "v"(b)); return d;
}
__device__ __forceinline__ v2f pk_fma(v2f a, v2f b, v2f c) {
    v2f d; asm("v_pk_fma_f32 %0, %1, %2, %3" : "=v"(d) : "v"(a), "v"(b), "v"(c)); return d;
}

// order-preserving bijection float -> uint32 (total order == float <)
__device__ __forceinline__ unsigned int fkey(float f) {
    unsigned int b = __float_as_uint(f);
    return b ^ (0x80000000u | (unsigned int)((int)b >> 31));
}

// ---------------- kernel B (filter): per (point, chunk) max of dot_j, cmax in [n][c] layout
// dot chain = exact XLA chain bits (mul + ascending fma) -> fmax selection is exact.
__global__ __launch_bounds__(256) void vq_filter_kernel(
        const float* __restrict__ z, const v2f* __restrict__ Epk,
        float* __restrict__ cmax) {
    __shared__ alignas(16) float4 sE4[CPB * PAIRS * 2];   // 16 KB: 8 chunks of pairs

    const int cbase = blockIdx.y * CPB;

    // ---- stage 8 chunk slices to LDS (coalesced float4 vector loads)
    {
        const float4* gE = (const float4*)(Epk + (size_t)cbase * PAIRS * 4);
        #pragma unroll
        for (int i = 0; i < (CPB * PAIRS * 2) / 256; ++i)   // 4 iters
            sE4[i * 256 + threadIdx.x] = gE[i * 256 + threadIdx.x];
    }

    const int n0 = blockIdx.x * (256 * FPPT) + threadIdx.x;

    v2f zv[FPPT][4];
    #pragma unroll
    for (int p = 0; p < FPPT; ++p) {
        int n = n0 + p * 256;
        int b = n >> 12, hw = n & 4095;
        const float* zp = z + b * 16384 + hw;
        zv[p][0] = (v2f){zp[0], zp[0]};
        zv[p][1] = (v2f){zp[CSTRIDE], zp[CSTRIDE]};
        zv[p][2] = (v2f){zp[2 * CSTRIDE], zp[2 * CSTRIDE]};
        zv[p][3] = (v2f){zp[3 * CSTRIDE], zp[3 * CSTRIDE]};
    }

    __syncthreads();

    float run[FPPT][CPB];                     // all indices unroll-static (no scratch)
    #pragma unroll
    for (int p = 0; p < FPPT; ++p)
        #pragma unroll
        for (int k = 0; k < CPB; ++k) run[p][k] = -__builtin_inff();

    #pragma unroll 2
    for (int t = 0; t < PAIRS; ++t) {
        #pragma unroll
        for (int k = 0; k < CPB; ++k) {
            // uniform LDS reads -> hardware broadcast, no bank conflicts
            float4 E01 = sE4[k * 128 + 2 * t];     // {e0.lo,e0.hi, e1.lo,e1.hi}
            float4 E23 = sE4[k * 128 + 2 * t + 1]; // {e2.lo,e2.hi, e3.lo,e3.hi}
            v2f e0 = {E01.x, E01.y};
            v2f e1 = {E01.z, E01.w};
            v2f e2 = {E23.x, E23.y};
            v2f e3 = {E23.z, E23.w};
            #pragma unroll
            for (int p = 0; p < FPPT; ++p) {
                v2f dot = pk_mul(zv[p][0], e0);    // z0*e0       (rn)
                dot = pk_fma(zv[p][1], e1, dot);   // ascending-k fma chain
                dot = pk_fma(zv[p][2], e2, dot);
                dot = pk_fma(zv[p][3], e3, dot);
                run[p][k] = fmaxf(fmaxf(dot.x, dot.y), run[p][k]);  // exact selection
            }
        }
    }

    // ---- write [n][c] layout: per point two contiguous float4 (32B/lane)
    #pragma unroll
    for (int p = 0; p < FPPT; ++p) {
        int n = n0 + p * 256;
        float4* dst = (float4*)(cmax + (size_t)n * CH + cbase);
        dst[0] = make_float4(run[p][0], run[p][1], run[p][2], run[p][3]);
        dst[1] = make_float4(run[p][4], run[p][5], run[p][6], run[p][7]);
    }
}

// ---------------- kernel C (resolve): one WAVE per point.
// Lane c reads cmax[n*64+c] (coalesced 256B/wave); shfl-reduce gmax; ballot -> survivor
// mask; coalesced exact rescan of survivors; min-key reduce = exact first-index argmin.
__global__ __launch_bounds__(RB) void vq_resolve_kernel(
        const float* __restrict__ z, const float4* __restrict__ E,
        const float* __restrict__ cmax,
        float* __restrict__ out, double* __restrict__ partial) {
    __shared__ double sdata[RB / 64];
    const int lane = threadIdx.x & 63;
    const int wid = threadIdx.x >> 6;
    const int n = blockIdx.x * (RB / 64) + wid;

    const int b = n >> 12;
    const int hw = n & 4095;
    const float* zp = z + b * 16384 + hw;
    float z0 = zp[0];
    float z1 = zp[CSTRIDE];
    float z2 = zp[2 * CSTRIDE];
    float z3 = zp[3 * CSTRIDE];
    float zz = __fmul_rn(z0, z0);
    zz = __fadd_rn(zz, __fmul_rn(z1, z1));
    zz = __fadd_rn(zz, __fmul_rn(z2, z2));
    zz = __fadd_rn(zz, __fmul_rn(z3, z3));

    // lane c holds chunk c's max-dot; wave max-reduce
    float cm = cmax[(size_t)n * CH + lane];
    float gmax = cm;
    #pragma unroll
    for (int off = 32; off; off >>= 1)
        gmax = fmaxf(gmax, __shfl_xor(gmax, off));

    // conservative bound (proven round 9): survivors have dot >= gmax - (2u + 1e-7)
    float u = __fmul_rn(__fadd_rn(zz, 0.01f), 2.38418579e-07f);   // (zz+.01)*2^-22
    float thr = __fsub_rn(gmax, __fadd_rn(__fadd_rn(u, u), 1e-7f));
    unsigned long long mask = __ballot(cm >= thr);   // wave-uniform, >=1 bit set

    // exact rescan of surviving chunks (coalesced: lane -> j0+lane, j0+64+lane)
    unsigned long long bkey = ~0ull;
    while (mask) {
        int c = __builtin_ctzll(mask);
        mask &= mask - 1ull;
        int j0 = c * CPC + lane;
        #pragma unroll
        for (int h = 0; h < 2; ++h) {
            int j = j0 + h * 64;
            float4 e = E[j];
            float ee = __fmul_rn(e.x, e.x);
            ee = __fadd_rn(ee, __fmul_rn(e.y, e.y));
            ee = __fadd_rn(ee, __fmul_rn(e.z, e.z));
            ee = __fadd_rn(ee, __fmul_rn(e.w, e.w));
            float dot = __fmul_rn(z0, e.x);
            dot = __fmaf_rn(z1, e.y, dot);
            dot = __fmaf_rn(z2, e.z, dot);
            dot = __fmaf_rn(z3, e.w, dot);
            float d = __fmaf_rn(-2.0f, dot, __fadd_rn(zz, ee));
            // key: (orderable d) << 32 | j  -> min key = min d, tie -> min j (first index)
            unsigned long long key =
                ((unsigned long long)fkey(d) << 32) | (unsigned int)j;
            bkey = key < bkey ? key : bkey;
        }
    }
    #pragma unroll
    for (int off = 32; off; off >>= 1) {
        unsigned long long o = __shfl_xor(bkey, off);
        bkey = o < bkey ? o : bkey;
    }
    int besti = (int)(unsigned int)(bkey & 0xFFFFFFFFull);

    if (lane == 0) {
        float4 e = E[besti];
        float* op = out + b * 16384 + hw;
        float t0 = __fsub_rn(e.x, z0);
        float t1 = __fsub_rn(e.y, z1);
        float t2 = __fsub_rn(e.z, z2);
        float t3 = __fsub_rn(e.w, z3);
        op[0]           = __fadd_rn(z0, t0);     // straight-through: z + (z_q - z)
        op[CSTRIDE]     = __fadd_rn(z1, t1);
        op[2 * CSTRIDE] = __fadd_rn(z2, t2);
        op[3 * CSTRIDE] = __fadd_rn(z3, t3);
        out[131073 + n] = (float)besti;          // indices as float32 (exact)
        double ds = (double)__fmul_rn(t0, t0) + (double)__fmul_rn(t1, t1)
                  + (double)__fmul_rn(t2, t2) + (double)__fmul_rn(t3, t3);
        sdata[wid] = ds;
    }
    __syncthreads();
    if (threadIdx.x == 0) {
        double s = 0.0;
        #pragma unroll
        for (int w = 0; w < RB / 64; ++w) s += sdata[w];
        partial[blockIdx.x] = s;
    }
}

// ---------------- kernel D: deterministic loss reduce (4096 partials)
__global__ void vq_loss_kernel(const double* __restrict__ partial, float* __restrict__ out) {
    __shared__ double sdata[256];
    int t = threadIdx.x;
    double s = 0.0;
    for (int i = t; i < 4096; i += 256) s += partial[i];
    sdata[t] = s;
    __syncthreads();
    #pragma unroll
    for (int st = 128; st > 0; st >>= 1) {
        if (t < st) sdata[t] += sdata[t + st];
        __syncthreads();
    }
    if (t == 0) {
        float m = (float)(sdata[0] / 131072.0);
        // loss = mean + BETA*mean (both means are numerically identical)
        out[131072] = __fadd_rn(m, __fmul_rn(0.25f, m));
    }
}

extern "C" void kernel_launch(void* const* d_in, const int* in_sizes, int n_in,
                              void* d_out, int out_size, void* d_ws, size_t ws_size,
                              hipStream_t stream) {
    const float* z = (const float*)d_in[0];
    const float4* E = (const float4*)d_in[1];
    float* out = (float*)d_out;

    char* ws = (char*)d_ws;
    v2f* Epk = (v2f*)ws;                                      // 128 KB
    float* cmaxb = (float*)(ws + 131072);                     // 32768*64 f32 = 8 MB, [n][c]
    double* partial = (double*)(ws + 131072 + (size_t)CH * N_POINTS * 4);  // 32 KB
    // total = 131072 + 8388608 + 32768 = 8552448 bytes (proven to fit)

    vq_prep_kernel<<<NPAIRS / 256, 256, 0, stream>>>(E, Epk);
    vq_filter_kernel<<<dim3(N_POINTS / (256 * FPPT), CH / CPB), 256, 0, stream>>>(z, Epk, cmaxb);
    vq_resolve_kernel<<<N_POINTS / (RB / 64), RB, 0, stream>>>(z, E, cmaxb, out, partial);
    vq_loss_kernel<<<1, 256, 0, stream>>>(partial, out);
}

// Round 12
// 55.748 us; speedup vs baseline: 1.1018x; 1.1018x over previous
//
#include <hip/hip_runtime.h>
#include <math.h>

typedef float v2f __attribute__((ext_vector_type(2)));

#define N_POINTS 32768
#define NUM_EMBED 8192
#define NPAIRS 4096
#define CH 64                                // chunks (fits 64-bit survivor mask)
#define CPC (NUM_EMBED / CH)                 // 128 candidates per chunk
#define PAIRS (NPAIRS / CH)                  // 64 pairs per chunk
#define PPT 8                                // filter points per thread
#define RB 512                               // resolve block threads (8 waves)
#define CSTRIDE 4096                         // 64*64, channel stride in z [B,C,H,W]

// tiled-transposed cmax index: groups of 8 points share a contiguous 2KB c-major tile
__device__ __forceinline__ size_t cmidx(int n, int c) {
    return (size_t)(n >> 3) * (CH * 8) + c * 8 + (n & 7);
}

// ---------------- kernel A: build pair-interleaved codebook (bits preserved)
__global__ void vq_prep_kernel(const float4* __restrict__ E, v2f* __restrict__ Epk) {
    int p = blockIdx.x * 256 + threadIdx.x;
    if (p < NPAIRS) {
        float4 a = E[2 * p];
        float4 b = E[2 * p + 1];
        Epk[4 * p + 0] = (v2f){a.x, b.x};
        Epk[4 * p + 1] = (v2f){a.y, b.y};
        Epk[4 * p + 2] = (v2f){a.z, b.z};
        Epk[4 * p + 3] = (v2f){a.w, b.w};
    }
}

// packed f32 ops forced via inline asm (per-half IEEE rn, bit-identical to scalar chain)
__device__ __forceinline__ v2f pk_mul(v2f a, v2f b) {
    v2f d; asm("v_pk_mul_f32 %0, %1, %2" : "=v"(d) : "v"(a), "v"(b)); return d;
}
__device__ __forceinline__ v2f pk_fma(v2f a, v2f b, v2f c) {
    v2f d; asm("v_pk_fma_f32 %0, %1, %2, %3" : "=v"(d) : "v"(a), "v"(b), "v"(c)); return d;
}

// order-preserving bijection float -> uint32 (total order == float <)
__device__ __forceinline__ unsigned int fkey(float f) {
    unsigned int b = __float_as_uint(f);
    return b ^ (0x80000000u | (unsigned int)((int)b >> 31));
}

// ---------------- kernel B (filter): per (point, chunk) max of dot_j (r10 structure)
// dot chain = exact XLA chain bits (mul + ascending fma) -> fmax selection is exact.
__global__ __launch_bounds__(256) void vq_filter_kernel(
        const float* __restrict__ z, const v2f* __restrict__ Epk,
        float* __restrict__ cmax) {
    __shared__ alignas(16) v2f sE[PAIRS * 4];   // 2 KB

    const int c = blockIdx.y;
    if (threadIdx.x < PAIRS * 2) {
        ((float4*)sE)[threadIdx.x] =
            ((const float4*)(Epk + (size_t)c * PAIRS * 4))[threadIdx.x];
    }

    const int n0 = blockIdx.x * (256 * PPT) + threadIdx.x;

    v2f zv[PPT][4];
    #pragma unroll
    for (int p = 0; p < PPT; ++p) {
        int n = n0 + p * 256;
        int b = n >> 12, hw = n & 4095;
        const float* zp = z + b * 16384 + hw;
        zv[p][0] = (v2f){zp[0], zp[0]};
        zv[p][1] = (v2f){zp[CSTRIDE], zp[CSTRIDE]};
        zv[p][2] = (v2f){zp[2 * CSTRIDE], zp[2 * CSTRIDE]};
        zv[p][3] = (v2f){zp[3 * CSTRIDE], zp[3 * CSTRIDE]};
    }

    __syncthreads();

    float run[PPT];
    #pragma unroll
    for (int p = 0; p < PPT; ++p) run[p] = -__builtin_inff();

    const float4* sE4 = (const float4*)sE;
    #pragma unroll 2
    for (int t = 0; t < PAIRS; ++t) {
        // uniform LDS reads -> hardware broadcast, no bank conflicts
        float4 E01 = sE4[2 * t];       // {e0.lo,e0.hi, e1.lo,e1.hi}
        float4 E23 = sE4[2 * t + 1];   // {e2.lo,e2.hi, e3.lo,e3.hi}
        v2f e0 = {E01.x, E01.y};
        v2f e1 = {E01.z, E01.w};
        v2f e2 = {E23.x, E23.y};
        v2f e3 = {E23.z, E23.w};
        #pragma unroll
        for (int p = 0; p < PPT; ++p) {
            v2f dot = pk_mul(zv[p][0], e0);       // z0*e0       (rn)
            dot = pk_fma(zv[p][1], e1, dot);      // ascending-k fma chain
            dot = pk_fma(zv[p][2], e2, dot);
            dot = pk_fma(zv[p][3], e3, dot);
            run[p] = fmaxf(fmaxf(dot.x, dot.y), run[p]);  // exact selection (v_max3)
        }
    }

    #pragma unroll
    for (int p = 0; p < PPT; ++p)
        cmax[cmidx(n0 + p * 256, c)] = run[p];
}

// ---------------- kernel C (resolve): one WAVE per point.
// Lane c reads cmax tile (block's 8 points share one contiguous 2KB region -> L1);
// shfl-reduce gmax; ballot -> survivor mask; coalesced exact rescan; min-key reduce.
__global__ __launch_bounds__(RB) void vq_resolve_kernel(
        const float* __restrict__ z, const float4* __restrict__ E,
        const float* __restrict__ cmax,
        float* __restrict__ out, double* __restrict__ partial) {
    __shared__ double sdata[RB / 64];
    const int lane = threadIdx.x & 63;
    const int wid = threadIdx.x >> 6;
    const int n = blockIdx.x * (RB / 64) + wid;

    const int b = n >> 12;
    const int hw = n & 4095;
    const float* zp = z + b * 16384 + hw;
    float z0 = zp[0];
    float z1 = zp[CSTRIDE];
    float z2 = zp[2 * CSTRIDE];
    float z3 = zp[3 * CSTRIDE];
    float zz = __fmul_rn(z0, z0);
    zz = __fadd_rn(zz, __fmul_rn(z1, z1));
    zz = __fadd_rn(zz, __fmul_rn(z2, z2));
    zz = __fadd_rn(zz, __fmul_rn(z3, z3));

    // lane c holds chunk c's max-dot; wave max-reduce
    float cm = cmax[cmidx(n, lane)];
    float gmax = cm;
    #pragma unroll
    for (int off = 32; off; off >>= 1)
        gmax = fmaxf(gmax, __shfl_xor(gmax, off));

    // conservative bound (proven round 9): survivors have dot >= gmax - (2u + 1e-7)
    float u = __fmul_rn(__fadd_rn(zz, 0.01f), 2.38418579e-07f);   // (zz+.01)*2^-22
    float thr = __fsub_rn(gmax, __fadd_rn(__fadd_rn(u, u), 1e-7f));
    unsigned long long mask = __ballot(cm >= thr);   // wave-uniform, >=1 bit set

    // exact rescan of surviving chunks (coalesced: lane -> j0+lane, j0+64+lane)
    unsigned long long bkey = ~0ull;
    while (mask) {
        int c = __builtin_ctzll(mask);
        mask &= mask - 1ull;
        int j0 = c * CPC + lane;
        #pragma unroll
        for (int h = 0; h < 2; ++h) {
            int j = j0 + h * 64;
            float4 e = E[j];
            float ee = __fmul_rn(e.x, e.x);
            ee = __fadd_rn(ee, __fmul_rn(e.y, e.y));
            ee = __fadd_rn(ee, __fmul_rn(e.z, e.z));
            ee = __fadd_rn(ee, __fmul_rn(e.w, e.w));
            float dot = __fmul_rn(z0, e.x);
            dot = __fmaf_rn(z1, e.y, dot);
            dot = __fmaf_rn(z2, e.z, dot);
            dot = __fmaf_rn(z3, e.w, dot);
            float d = __fmaf_rn(-2.0f, dot, __fadd_rn(zz, ee));
            // key: (orderable d) << 32 | j  -> min key = min d, tie -> min j (first index)
            unsigned long long key =
                ((unsigned long long)fkey(d) << 32) | (unsigned int)j;
            bkey = key < bkey ? key : bkey;
        }
    }
    #pragma unroll
    for (int off = 32; off; off >>= 1) {
        unsigned long long o = __shfl_xor(bkey, off);
        bkey = o < bkey ? o : bkey;
    }
    int besti = (int)(unsigned int)(bkey & 0xFFFFFFFFull);

    if (lane == 0) {
        float4 e = E[besti];
        float* op = out + b * 16384 + hw;
        float t0 = __fsub_rn(e.x, z0);
        float t1 = __fsub_rn(e.y, z1);
        float t2 = __fsub_rn(e.z, z2);
        float t3 = __fsub_rn(e.w, z3);
        op[0]           = __fadd_rn(z0, t0);     // straight-through: z + (z_q - z)
        op[CSTRIDE]     = __fadd_rn(z1, t1);
        op[2 * CSTRIDE] = __fadd_rn(z2, t2);
        op[3 * CSTRIDE] = __fadd_rn(z3, t3);
        out[131073 + n] = (float)besti;          // indices as float32 (exact)
        double ds = (double)__fmul_rn(t0, t0) + (double)__fmul_rn(t1, t1)
                  + (double)__fmul_rn(t2, t2) + (double)__fmul_rn(t3, t3);
        sdata[wid] = ds;
    }
    __syncthreads();
    if (threadIdx.x == 0) {
        double s = 0.0;
        #pragma unroll
        for (int w = 0; w < RB / 64; ++w) s += sdata[w];
        partial[blockIdx.x] = s;
    }
}

// ---------------- kernel D: deterministic loss reduce (4096 partials)
__global__ void vq_loss_kernel(const double* __restrict__ partial, float* __restrict__ out) {
    __shared__ double sdata[256];
    int t = threadIdx.x;
    double s = 0.0;
    for (int i = t; i < 4096; i += 256) s += partial[i];
    sdata[t] = s;
    __syncthreads();
    #pragma unroll
    for (int st = 128; st > 0; st >>= 1) {
        if (t < st) sdata[t] += sdata[t + st];
        __syncthreads();
    }
    if (t == 0) {
        float m = (float)(sdata[0] / 131072.0);
        // loss = mean + BETA*mean (both means are numerically identical)
        out[131072] = __fadd_rn(m, __fmul_rn(0.25f, m));
    }
}

extern "C" void kernel_launch(void* const* d_in, const int* in_sizes, int n_in,
                              void* d_out, int out_size, void* d_ws, size_t ws_size,
                              hipStream_t stream) {
    const float* z = (const float*)d_in[0];
    const float4* E = (const float4*)d_in[1];
    float* out = (float*)d_out;

    char* ws = (char*)d_ws;
    v2f* Epk = (v2f*)ws;                                      // 128 KB
    float* cmaxb = (float*)(ws + 131072);                     // 8 MB, tiled [n/8][c][n%8]
    double* partial = (double*)(ws + 131072 + (size_t)CH * N_POINTS * 4);  // 32 KB
    // total = 131072 + 8388608 + 32768 = 8552448 bytes (proven to fit)

    vq_prep_kernel<<<NPAIRS / 256, 256, 0, stream>>>(E, Epk);
    vq_filter_kernel<<<dim3(N_POINTS / (256 * PPT), CH), 256, 0, stream>>>(z, Epk, cmaxb);
    vq_resolve_kernel<<<N_POINTS / (RB / 64), RB, 0, stream>>>(z, E, cmaxb, out, partial);
    vq_loss_kernel<<<1, 256, 0, stream>>>(partial, out);
}